// Round 2
// baseline (247.916 us; speedup 1.0000x reference)
//
#include <hip/hip_runtime.h>
#include <stdint.h>

#define NROWS 8192
#define MCOLS 8192
#define DDIM  64

typedef _Float16 half8  __attribute__((ext_vector_type(8)));
typedef float    floatx16 __attribute__((ext_vector_type(16)));

// ---------- monotone float <-> uint key (for atomicMax argmax) ----------
__device__ __forceinline__ unsigned f2key(float f) {
  unsigned u = __float_as_uint(f);
  return (u & 0x80000000u) ? ~u : (u | 0x80000000u);
}
__device__ __forceinline__ float key2f(unsigned k) {
  unsigned u = (k & 0x80000000u) ? (k & 0x7fffffffu) : ~k;
  return __uint_as_float(u);
}

// ---------- zero accumulators (ws poisoned 0xAA every call) ----------
__global__ void init_kernel(unsigned long long* __restrict__ rk,
                            unsigned long long* __restrict__ ck,
                            float* __restrict__ rs, float* __restrict__ cs) {
  int i = blockIdx.x * 256 + threadIdx.x;
  if (i < NROWS) { rk[i] = 0ull; rs[i] = 0.0f; }
  if (i < MCOLS) { ck[i] = 0ull; cs[i] = 0.0f; }
}

// ---------- squared norms: one wave per row (exact fp32) ----------
__global__ void norms_kernel(const float* __restrict__ x, const float* __restrict__ y,
                             float* __restrict__ xn, float* __restrict__ yn) {
  int gt   = blockIdx.x * 256 + threadIdx.x;
  int wave = gt >> 6;
  int lane = threadIdx.x & 63;
  const float* src; float* dst; int row;
  if (wave < NROWS) { src = x; dst = xn; row = wave; }
  else              { src = y; dst = yn; row = wave - NROWS; }
  float v = src[(size_t)row * DDIM + lane];
  float s = v * v;
  #pragma unroll
  for (int off = 32; off > 0; off >>= 1) s += __shfl_down(s, off);
  if (lane == 0) dst[row] = s;
}

// ---------- split fp32 -> (fp16 hi, fp16 lo*2^11), packed in MFMA frag order ----
// A/B operand layout for v_mfma_f32_32x32x16_f16 (assumed, symmetric to verified
// 16x16x32): lane holds m = lane&31, k = (lane>>5)*8 + j, j in [0,8).
// Packed pos within a row: pos = q*32 + kc*8 + j  where k = kc*16 + q*8 + j.
__global__ void convert_kernel(const float* __restrict__ x, const float* __restrict__ y,
                               _Float16* __restrict__ xh, _Float16* __restrict__ xl,
                               _Float16* __restrict__ yh, _Float16* __restrict__ yl) {
  int gid = blockIdx.x * 256 + threadIdx.x;          // 0 .. 2*8192*64-1
  const float* src; _Float16 *dh, *dl; int idx;
  if (gid < NROWS * DDIM) { src = x; dh = xh; dl = xl; idx = gid; }
  else                    { src = y; dh = yh; dl = yl; idx = gid - NROWS * DDIM; }
  float f = src[idx];
  _Float16 h = (_Float16)f;
  _Float16 l = (_Float16)((f - (float)h) * 2048.0f);
  int row = idx >> 6, k = idx & 63;
  int pos = (row << 6) + ((k >> 3) & 1) * 32 + ((k >> 4) << 3) + (k & 7);
  dh[pos] = h; dl[pos] = l;
}

// ---------- main pass: 128x128 tile per block, MFMA, no LDS ----------
__global__ __launch_bounds__(256, 2) void mfma_tile_kernel(
    const _Float16* __restrict__ xh, const _Float16* __restrict__ xl,
    const _Float16* __restrict__ yh, const _Float16* __restrict__ yl,
    const float* __restrict__ xn, const float* __restrict__ yn,
    unsigned long long* __restrict__ row_key, float* __restrict__ row_sum,
    unsigned long long* __restrict__ col_key, float* __restrict__ col_sum)
{
  const int wave = threadIdx.x >> 6;
  const int lane = threadIdx.x & 63;
  const int l31  = lane & 31;
  const int q    = lane >> 5;
  const int rb   = blockIdx.y * 4 + wave;          // global 32-row block of x
  const int bj   = blockIdx.x;

  // ---- A fragments: 4 K-chunks of hi and lo, straight from global ----
  const half8* pah = (const half8*)(xh + ((size_t)(rb * 32 + l31) * 64 + q * 32));
  const half8* pal = (const half8*)(xl + ((size_t)(rb * 32 + l31) * 64 + q * 32));
  half8 ah[4], al[4];
  #pragma unroll
  for (int kc = 0; kc < 4; ++kc) { ah[kc] = pah[kc]; al[kc] = pal[kc]; }

  // ---- per-row constants and running state (16 C-regs -> 16 rows/lane) ----
  float xnr[16], rowsum[16];
  unsigned long long rowkey[16];
  int rowloc[16];
  #pragma unroll
  for (int r = 0; r < 16; ++r) {
    rowloc[r] = (r & 3) + 8 * (r >> 2) + 4 * q;    // C/D row mapping (m74/m101)
    xnr[r]    = xn[rb * 32 + rowloc[r]];
    rowsum[r] = 0.0f;
    rowkey[r] = 0ull;
  }

  const float c2scale = 1.0f / 2048.0f;

  #pragma unroll
  for (int cb = 0; cb < 4; ++cb) {
    const int cbg   = bj * 4 + cb;                 // global 32-col block of y
    const int jglob = cbg * 32 + l31;
    const half8* pbh = (const half8*)(yh + ((size_t)(cbg * 32 + l31) * 64 + q * 32));
    const half8* pbl = (const half8*)(yl + ((size_t)(cbg * 32 + l31) * 64 + q * 32));

    floatx16 c1 = {}, c2 = {};
    #pragma unroll
    for (int kc = 0; kc < 4; ++kc) {
      half8 bh = pbh[kc], bl = pbl[kc];
      c1 = __builtin_amdgcn_mfma_f32_32x32x16_f16(ah[kc], bh, c1, 0, 0, 0);
      c2 = __builtin_amdgcn_mfma_f32_32x32x16_f16(al[kc], bh, c2, 0, 0, 0);
      c2 = __builtin_amdgcn_mfma_f32_32x32x16_f16(ah[kc], bl, c2, 0, 0, 0);
    }

    float ync = yn[jglob];
    float colsum = 0.0f;
    unsigned long long colkey = 0ull;

    #pragma unroll
    for (int r = 0; r < 16; ++r) {
      float dot = fmaf(c2[r], c2scale, c1[r]);
      float sq  = fmaxf(fmaf(-2.0f, dot, xnr[r] + ync), 0.0f);
      float d   = 2.0f - sqrtf(sq);
      float e   = __expf(d);
      rowsum[r] += e;
      colsum    += e;
      unsigned k32 = f2key(d);
      int iglob = rb * 32 + rowloc[r];
      unsigned long long rk =
          ((unsigned long long)k32 << 32) | (unsigned long long)(unsigned)(~(unsigned)jglob);
      unsigned long long ck =
          ((unsigned long long)k32 << 32) | (unsigned long long)(unsigned)(~(unsigned)iglob);
      if (rk > rowkey[r]) rowkey[r] = rk;
      if (ck > colkey)    colkey    = ck;
    }

    // combine the two q-halves (rows 0..31 of this col-block)
    colsum += __shfl_xor(colsum, 32);
    unsigned long long o = __shfl_xor(colkey, 32);
    if (o > colkey) colkey = o;
    if (q == 0) {
      atomicAdd(col_sum + jglob, colsum);
      atomicMax(col_key + jglob, colkey);
    }
  }

  // ---- row reduce: butterfly across the 32 lane-columns ----
  #pragma unroll
  for (int off = 1; off < 32; off <<= 1) {
    #pragma unroll
    for (int r = 0; r < 16; ++r) {
      rowsum[r] += __shfl_xor(rowsum[r], off);
      unsigned long long o = __shfl_xor(rowkey[r], off);
      if (o > rowkey[r]) rowkey[r] = o;
    }
  }
  if (l31 == 0) {
    #pragma unroll
    for (int r = 0; r < 16; ++r) {
      int iglob = rb * 32 + rowloc[r];
      atomicAdd(row_sum + iglob, rowsum[r]);
      atomicMax(row_key + iglob, rowkey[r]);
    }
  }
}

// ---------- finalize: unpack keys, mutual test, write outputs ----------
__global__ void finalize_kernel(const unsigned long long* __restrict__ row_key,
                                const float* __restrict__ row_sum,
                                const unsigned long long* __restrict__ col_key,
                                const float* __restrict__ col_sum,
                                float* __restrict__ out)
{
  int j = blockIdx.x * 256 + threadIdx.x;
  if (j >= MCOLS) return;
  unsigned long long ck = col_key[j];
  int   ci   = (int)(~(unsigned)ck);
  float cmax = key2f((unsigned)(ck >> 32));
  float lp_col = cmax - logf(col_sum[j]);

  unsigned long long rk = row_key[ci];
  int   rj   = (int)(~(unsigned)rk);
  float rmax = key2f((unsigned)(rk >> 32));
  float lp_row = rmax - logf(row_sum[ci]);

  int mut = (rj == j);
  out[j]                 = mut ? (lp_row + lp_col) : 0.0f;
  out[MCOLS + 2 * j + 0] = (float)ci;
  out[MCOLS + 2 * j + 1] = (float)j;
  out[3 * MCOLS + j]     = mut ? 1.0f : 0.0f;
}

extern "C" void kernel_launch(void* const* d_in, const int* in_sizes, int n_in,
                              void* d_out, int out_size, void* d_ws, size_t ws_size,
                              hipStream_t stream) {
  const float* x = (const float*)d_in[0];
  const float* y = (const float*)d_in[1];
  float* out = (float*)d_out;

  char* ws = (char*)d_ws;
  unsigned long long* row_key = (unsigned long long*)(ws);            // 64 KB
  unsigned long long* col_key = (unsigned long long*)(ws + 65536);    // 64 KB
  float* row_sum = (float*)(ws + 131072);                             // 32 KB
  float* col_sum = (float*)(ws + 163840);                             // 32 KB
  float* xn      = (float*)(ws + 196608);                             // 32 KB
  float* yn      = (float*)(ws + 229376);                             // 32 KB
  _Float16* xh = (_Float16*)(ws + 262144);                            // 1 MB each
  _Float16* xl = (_Float16*)(ws + 262144 + 1048576);
  _Float16* yh = (_Float16*)(ws + 262144 + 2097152);
  _Float16* yl = (_Float16*)(ws + 262144 + 3145728);

  convert_kernel<<<4096, 256, 0, stream>>>(x, y, xh, xl, yh, yl);
  norms_kernel<<<4096, 256, 0, stream>>>(x, y, xn, yn);
  init_kernel<<<32, 256, 0, stream>>>(row_key, col_key, row_sum, col_sum);
  dim3 grid(MCOLS / 128, NROWS / 128);     // 64 x 64 tiles
  mfma_tile_kernel<<<grid, 256, 0, stream>>>(xh, xl, yh, yl, xn, yn,
                                             row_key, row_sum, col_key, col_sum);
  finalize_kernel<<<32, 256, 0, stream>>>(row_key, row_sum, col_key, col_sum, out);
}

// Round 3
// 148.163 us; speedup vs baseline: 1.6733x; 1.6733x over previous
//
#include <hip/hip_runtime.h>
#include <stdint.h>

#define NROWS 8192
#define MCOLS 8192
#define DDIM  64

typedef _Float16 half8   __attribute__((ext_vector_type(8)));
typedef float    floatx4 __attribute__((ext_vector_type(4)));

// ---------- monotone float <-> uint key (for atomicMax argmax) ----------
__device__ __forceinline__ unsigned f2key(float f) {
  unsigned u = __float_as_uint(f);
  return (u & 0x80000000u) ? ~u : (u | 0x80000000u);
}
__device__ __forceinline__ float key2f(unsigned k) {
  unsigned u = (k & 0x80000000u) ? (k & 0x7fffffffu) : ~k;
  return __uint_as_float(u);
}

// ---------- zero accumulators (ws poisoned 0xAA every call) ----------
__global__ void init_kernel(unsigned long long* __restrict__ rk,
                            unsigned long long* __restrict__ ck,
                            float* __restrict__ rs, float* __restrict__ cs) {
  int i = blockIdx.x * 256 + threadIdx.x;
  if (i < NROWS) { rk[i] = 0ull; rs[i] = 0.0f; }
  if (i < MCOLS) { ck[i] = 0ull; cs[i] = 0.0f; }
}

// ---------- squared norms: one wave per row (exact fp32) ----------
__global__ void norms_kernel(const float* __restrict__ x, const float* __restrict__ y,
                             float* __restrict__ xn, float* __restrict__ yn) {
  int gt   = blockIdx.x * 256 + threadIdx.x;
  int wave = gt >> 6;
  int lane = threadIdx.x & 63;
  const float* src; float* dst; int row;
  if (wave < NROWS) { src = x; dst = xn; row = wave; }
  else              { src = y; dst = yn; row = wave - NROWS; }
  float v = src[(size_t)row * DDIM + lane];
  float s = v * v;
  #pragma unroll
  for (int off = 32; off > 0; off >>= 1) s += __shfl_down(s, off);
  if (lane == 0) dst[row] = s;
}

// ---------- fp32 -> (fp16 hi, fp16 lo*2^11) packed in MFMA fragment-lane order --
// 16x16x32 f16 A/B operand layout: m = lane&15, k = (lane>>4)*8 + j, j in [0,8),
// chunk c covers k += 32c. Packed unit index: (panel*2 + c)*64 + lane, 8 halves each.
__global__ void convert_kernel(const float* __restrict__ x, const float* __restrict__ y,
                               _Float16* __restrict__ xh, _Float16* __restrict__ xl,
                               _Float16* __restrict__ yh, _Float16* __restrict__ yl) {
  int gid = blockIdx.x * 256 + threadIdx.x;        // 0 .. 131071
  const float* src; _Float16 *dh, *dl; int t;
  if (gid < 65536) { src = x; dh = xh; dl = xl; t = gid; }
  else             { src = y; dh = yh; dl = yl; t = gid - 65536; }
  int lane = t & 63;
  int c    = (t >> 6) & 1;
  int p    = t >> 7;                               // 16-row panel, 0..511
  int row  = p * 16 + (lane & 15);
  int k0   = c * 32 + ((lane >> 4) << 3);
  const float* s = src + (size_t)row * DDIM + k0;
  _Float16 hbuf[8], lbuf[8];
  #pragma unroll
  for (int j = 0; j < 8; ++j) {
    float f = s[j];
    _Float16 h = (_Float16)f;
    hbuf[j] = h;
    lbuf[j] = (_Float16)((f - (float)h) * 2048.0f);
  }
  size_t o = (size_t)t * 8;
  *(half8*)(dh + o) = *(half8*)hbuf;
  *(half8*)(dl + o) = *(half8*)lbuf;
}

// ---------- main pass: block = 8 waves = 128 rows x 256 cols, 16x16x32 MFMA ------
__global__ __launch_bounds__(512, 4) void mfma_tile_kernel(
    const _Float16* __restrict__ xh, const _Float16* __restrict__ xl,
    const _Float16* __restrict__ yh, const _Float16* __restrict__ yl,
    const float* __restrict__ xn, const float* __restrict__ yn,
    unsigned long long* __restrict__ row_key, float* __restrict__ row_sum,
    unsigned long long* __restrict__ col_key, float* __restrict__ col_sum)
{
  __shared__ unsigned long long lkey[256 * 8];   // [col][wave] 16 KB
  __shared__ float              lsum[256 * 8];   //              8 KB

  const int wave  = threadIdx.x >> 6;
  const int lane  = threadIdx.x & 63;
  const int l15   = lane & 15;
  const int g     = lane >> 4;                   // row-group 0..3
  const int ap    = blockIdx.y * 8 + wave;       // A panel (16 rows)
  const int rbase = ap * 16;

  // ---- A fragments (coalesced: 16 B/lane) ----
  const size_t abase = (size_t)ap * 128 + lane;  // in half8 units
  half8 ah0 = ((const half8*)xh)[abase];
  half8 ah1 = ((const half8*)xh)[abase + 64];
  half8 al0 = ((const half8*)xl)[abase];
  half8 al1 = ((const half8*)xl)[abase + 64];

  // ---- per-row running state: 4 rows/lane (C/D: col=lane&15, row=g*4+reg) ----
  float xne[4], rsum[4], rmax[4]; int ridx[4];
  #pragma unroll
  for (int r = 0; r < 4; ++r) {
    xne[r]  = xn[rbase + g * 4 + r];
    rsum[r] = 0.0f; rmax[r] = -3.4e38f; ridx[r] = 0;
  }

  // ---- j-loop over 16 col panels, B prefetched one tile ahead ----
  const int cp0 = blockIdx.x * 16;               // first col panel
  const size_t bbase = (size_t)cp0 * 128 + lane;
  half8 nbh0 = ((const half8*)yh)[bbase];
  half8 nbh1 = ((const half8*)yh)[bbase + 64];
  half8 nbl0 = ((const half8*)yl)[bbase];
  half8 nbl1 = ((const half8*)yl)[bbase + 64];

  for (int jt = 0; jt < 16; ++jt) {
    half8 bh0 = nbh0, bh1 = nbh1, bl0 = nbl0, bl1 = nbl1;
    if (jt < 15) {
      size_t nb = bbase + (size_t)(jt + 1) * 128;
      nbh0 = ((const half8*)yh)[nb];  nbh1 = ((const half8*)yh)[nb + 64];
      nbl0 = ((const half8*)yl)[nb];  nbl1 = ((const half8*)yl)[nb + 64];
    }

    floatx4 c1 = {}, c2 = {};
    c1 = __builtin_amdgcn_mfma_f32_16x16x32_f16(ah0, bh0, c1, 0, 0, 0);
    c1 = __builtin_amdgcn_mfma_f32_16x16x32_f16(ah1, bh1, c1, 0, 0, 0);
    c2 = __builtin_amdgcn_mfma_f32_16x16x32_f16(al0, bh0, c2, 0, 0, 0);
    c2 = __builtin_amdgcn_mfma_f32_16x16x32_f16(al1, bh1, c2, 0, 0, 0);
    c2 = __builtin_amdgcn_mfma_f32_16x16x32_f16(ah0, bl0, c2, 0, 0, 0);
    c2 = __builtin_amdgcn_mfma_f32_16x16x32_f16(ah1, bl1, c2, 0, 0, 0);

    const int col = cp0 * 16 + jt * 16 + l15;
    const float ync = yn[col];
    float csum = 0.0f, cmax = -3.4e38f; int cidx = 0;

    #pragma unroll
    for (int r = 0; r < 4; ++r) {
      float dot = fmaf(c2[r], (1.0f / 2048.0f), c1[r]);
      float sq  = fmaxf(fmaf(-2.0f, dot, xne[r] + ync), 0.0f);
      float d   = 2.0f - sqrtf(sq);
      float e   = __expf(d);
      rsum[r] += e;  csum += e;
      if (d > rmax[r]) { rmax[r] = d; ridx[r] = col; }           // cols ascend -> first-max
      if (d > cmax)    { cmax = d;    cidx = rbase + g * 4 + r; } // rows ascend -> first-max
    }

    // merge col partials across the 4 row-groups (key packs tie-break: ~idx)
    unsigned long long ck =
        ((unsigned long long)f2key(cmax) << 32) | (unsigned long long)(unsigned)(~(unsigned)cidx);
    #pragma unroll
    for (int off = 16; off < 64; off <<= 1) {
      csum += __shfl_xor(csum, off);
      unsigned long long o = __shfl_xor(ck, off);
      if (o > ck) ck = o;
    }
    if (g == 0) {
      int lc = jt * 16 + l15;
      lkey[lc * 8 + wave] = ck;
      lsum[lc * 8 + wave] = csum;
    }
  }

  // ---- row reduce: butterfly across the 16 lane-columns ----
  unsigned long long rk[4];
  #pragma unroll
  for (int r = 0; r < 4; ++r)
    rk[r] = ((unsigned long long)f2key(rmax[r]) << 32) |
            (unsigned long long)(unsigned)(~(unsigned)ridx[r]);
  #pragma unroll
  for (int off = 1; off < 16; off <<= 1) {
    #pragma unroll
    for (int r = 0; r < 4; ++r) {
      rsum[r] += __shfl_xor(rsum[r], off);
      unsigned long long o = __shfl_xor(rk[r], off);
      if (o > rk[r]) rk[r] = o;
    }
  }
  if (l15 == 0) {
    #pragma unroll
    for (int r = 0; r < 4; ++r) {
      atomicMax(row_key + rbase + g * 4 + r, rk[r]);
      atomicAdd(row_sum + rbase + g * 4 + r, rsum[r]);
    }
  }

  // ---- block-level col merge (8 waves -> 1 atomic pair per col) ----
  __syncthreads();
  int t = threadIdx.x;
  if (t < 256) {
    unsigned long long k = lkey[t * 8];
    float s = lsum[t * 8];
    #pragma unroll
    for (int w = 1; w < 8; ++w) {
      unsigned long long o = lkey[t * 8 + w];
      if (o > k) k = o;
      s += lsum[t * 8 + w];
    }
    int col = blockIdx.x * 256 + t;
    atomicMax(col_key + col, k);
    atomicAdd(col_sum + col, s);
  }
}

// ---------- finalize: unpack keys, mutual test, write outputs ----------
__global__ void finalize_kernel(const unsigned long long* __restrict__ row_key,
                                const float* __restrict__ row_sum,
                                const unsigned long long* __restrict__ col_key,
                                const float* __restrict__ col_sum,
                                float* __restrict__ out)
{
  int j = blockIdx.x * 256 + threadIdx.x;
  if (j >= MCOLS) return;
  unsigned long long ck = col_key[j];
  int   ci   = (int)(~(unsigned)ck);
  float cmax = key2f((unsigned)(ck >> 32));
  float lp_col = cmax - logf(col_sum[j]);

  unsigned long long rk = row_key[ci];
  int   rj   = (int)(~(unsigned)rk);
  float rmax = key2f((unsigned)(rk >> 32));
  float lp_row = rmax - logf(row_sum[ci]);

  int mut = (rj == j);
  out[j]                 = mut ? (lp_row + lp_col) : 0.0f;
  out[MCOLS + 2 * j + 0] = (float)ci;
  out[MCOLS + 2 * j + 1] = (float)j;
  out[3 * MCOLS + j]     = mut ? 1.0f : 0.0f;
}

extern "C" void kernel_launch(void* const* d_in, const int* in_sizes, int n_in,
                              void* d_out, int out_size, void* d_ws, size_t ws_size,
                              hipStream_t stream) {
  const float* x = (const float*)d_in[0];
  const float* y = (const float*)d_in[1];
  float* out = (float*)d_out;

  char* ws = (char*)d_ws;
  unsigned long long* row_key = (unsigned long long*)(ws);            // 64 KB
  unsigned long long* col_key = (unsigned long long*)(ws + 65536);    // 64 KB
  float* row_sum = (float*)(ws + 131072);                             // 32 KB
  float* col_sum = (float*)(ws + 163840);                             // 32 KB
  float* xn      = (float*)(ws + 196608);                             // 32 KB
  float* yn      = (float*)(ws + 229376);                             // 32 KB
  _Float16* xh = (_Float16*)(ws + 262144);                            // 1 MB each
  _Float16* xl = (_Float16*)(ws + 262144 + 1048576);
  _Float16* yh = (_Float16*)(ws + 262144 + 2097152);
  _Float16* yl = (_Float16*)(ws + 262144 + 3145728);

  convert_kernel<<<512, 256, 0, stream>>>(x, y, xh, xl, yh, yl);
  norms_kernel<<<4096, 256, 0, stream>>>(x, y, xn, yn);
  init_kernel<<<32, 256, 0, stream>>>(row_key, col_key, row_sum, col_sum);
  dim3 grid(MCOLS / 256, NROWS / 128);     // 32 x 64 blocks, 512 threads
  mfma_tile_kernel<<<grid, 512, 0, stream>>>(xh, xl, yh, yl, xn, yn,
                                             row_key, row_sum, col_key, col_sum);
  finalize_kernel<<<32, 256, 0, stream>>>(row_key, row_sum, col_key, col_sum, out);
}

// Round 4
// 128.312 us; speedup vs baseline: 1.9321x; 1.1547x over previous
//
#include <hip/hip_runtime.h>
#include <stdint.h>

#define NROWS 8192
#define MCOLS 8192
#define DDIM  64

typedef _Float16 half8   __attribute__((ext_vector_type(8)));
typedef float    floatx4 __attribute__((ext_vector_type(4)));

// ---------- monotone float <-> uint key (for atomicMax argmax) ----------
__device__ __forceinline__ unsigned f2key(float f) {
  unsigned u = __float_as_uint(f);
  return (u & 0x80000000u) ? ~u : (u | 0x80000000u);
}
__device__ __forceinline__ float key2f(unsigned k) {
  unsigned u = (k & 0x80000000u) ? (k & 0x7fffffffu) : ~k;
  return __uint_as_float(u);
}

// ---------- fused: fp16-split conversion + row norms + accumulator init -------
// Packs fp32 -> (fp16 hi, fp16 lo*2^11) in 16x16x32 MFMA fragment-lane order:
// unit t = (panel*2 + c)*64 + lane holds row = panel*16+(lane&15),
// k = c*32 + (lane>>4)*8 + j, j in [0,8).  Also computes row squared-norms
// (LDS atomic adds) and zeroes the global reduction accumulators.
__global__ void convert_kernel(const float* __restrict__ x, const float* __restrict__ y,
                               _Float16* __restrict__ xh, _Float16* __restrict__ xl,
                               _Float16* __restrict__ yh, _Float16* __restrict__ yl,
                               float* __restrict__ xn, float* __restrict__ yn,
                               unsigned long long* __restrict__ rk,
                               unsigned long long* __restrict__ ck,
                               float* __restrict__ rs, float* __restrict__ cs) {
  __shared__ float lnorm[32];
  const int gid = blockIdx.x * 256 + threadIdx.x;      // 0 .. 131071
  if (gid < 8192) { rk[gid] = 0ull; rs[gid] = 0.0f; ck[gid] = 0ull; cs[gid] = 0.0f; }
  if (threadIdx.x < 32) lnorm[threadIdx.x] = 0.0f;
  __syncthreads();

  const float* src; _Float16 *dh, *dl; float* nout; int t, rowbase;
  if (gid < 65536) { src = x; dh = xh; dl = xl; nout = xn; t = gid;
                     rowbase = blockIdx.x * 32; }
  else             { src = y; dh = yh; dl = yl; nout = yn; t = gid - 65536;
                     rowbase = (blockIdx.x - 256) * 32; }

  const int lane = t & 63;
  const int c    = (t >> 6) & 1;
  const int p    = t >> 7;
  const int row  = p * 16 + (lane & 15);
  const int k0   = c * 32 + ((lane >> 4) << 3);
  const float* s = src + (size_t)row * DDIM + k0;

  _Float16 hbuf[8], lbuf[8];
  float s8 = 0.0f;
  #pragma unroll
  for (int j = 0; j < 8; ++j) {
    float f = s[j];
    _Float16 h = (_Float16)f;
    hbuf[j] = h;
    lbuf[j] = (_Float16)((f - (float)h) * 2048.0f);
    s8 = fmaf(f, f, s8);
  }
  size_t o = (size_t)t * 8;
  *(half8*)(dh + o) = *(half8*)hbuf;
  *(half8*)(dl + o) = *(half8*)lbuf;

  atomicAdd(&lnorm[((p & 1) << 4) | (t & 15)], s8);
  __syncthreads();
  if (threadIdx.x < 32) nout[rowbase + threadIdx.x] = lnorm[threadIdx.x];
}

// ---------- main pass: block = 4 waves, each wave 32 rows x 256 cols ----------
__global__ __launch_bounds__(256, 4) void mfma_tile_kernel(
    const _Float16* __restrict__ xh, const _Float16* __restrict__ xl,
    const _Float16* __restrict__ yh, const _Float16* __restrict__ yl,
    const float* __restrict__ xn, const float* __restrict__ yn,
    unsigned long long* __restrict__ row_key, float* __restrict__ row_sum,
    unsigned long long* __restrict__ col_key, float* __restrict__ col_sum)
{
  __shared__ unsigned long long lkey[256];   // per-block col keys (2 KB)
  __shared__ float              lsum[256];   // per-block col sums (1 KB)

  const int wave = threadIdx.x >> 6;
  const int lane = threadIdx.x & 63;
  const int l15  = lane & 15;
  const int g    = lane >> 4;                // row-group 0..3
  const int ap0  = blockIdx.y * 8 + wave * 2;       // first of 2 A panels
  const int ro   = ap0 * 16 + g * 4;                // first row this lane covers
  const int colbase = blockIdx.x * 256;

  lkey[threadIdx.x] = 0ull;
  lsum[threadIdx.x] = 0.0f;
  __syncthreads();

  // ---- A fragments: 2 panels x (2 hi + 2 lo chunks), 32 VGPRs ----
  const half8* xh8 = (const half8*)xh;
  const half8* xl8 = (const half8*)xl;
  const half8* yh8 = (const half8*)yh;
  const half8* yl8 = (const half8*)yl;
  const size_t a0 = (size_t)ap0 * 128 + lane;
  half8 Ah[2][2], Al[2][2];
  #pragma unroll
  for (int p = 0; p < 2; ++p) {
    Ah[p][0] = xh8[a0 + p * 128];      Ah[p][1] = xh8[a0 + p * 128 + 64];
    Al[p][0] = xl8[a0 + p * 128];      Al[p][1] = xl8[a0 + p * 128 + 64];
  }

  // ---- per-row state: 8 rows/lane ----
  float xne[8], rsum[8], rmax[8]; int ridx[8];
  #pragma unroll
  for (int s = 0; s < 8; ++s) {
    xne[s]  = xn[ro + ((s >> 2) << 4) + (s & 3)];
    rsum[s] = 0.0f; rmax[s] = -3.4e38f; ridx[s] = 0;
  }

  for (int jt = 0; jt < 16; ++jt) {
    const size_t b0 = (size_t)(blockIdx.x * 16 + jt) * 128 + lane;
    const half8 bh0 = yh8[b0], bh1 = yh8[b0 + 64];
    const half8 bl0 = yl8[b0], bl1 = yl8[b0 + 64];
    const int col = colbase + jt * 16 + l15;
    const float ync = yn[col];

    float dv[8], ev[8];
    #pragma unroll
    for (int p = 0; p < 2; ++p) {
      floatx4 c1 = {}, c2 = {};
      c1 = __builtin_amdgcn_mfma_f32_16x16x32_f16(Ah[p][0], bh0, c1, 0, 0, 0);
      c1 = __builtin_amdgcn_mfma_f32_16x16x32_f16(Ah[p][1], bh1, c1, 0, 0, 0);
      c2 = __builtin_amdgcn_mfma_f32_16x16x32_f16(Al[p][0], bh0, c2, 0, 0, 0);
      c2 = __builtin_amdgcn_mfma_f32_16x16x32_f16(Al[p][1], bh1, c2, 0, 0, 0);
      c2 = __builtin_amdgcn_mfma_f32_16x16x32_f16(Ah[p][0], bl0, c2, 0, 0, 0);
      c2 = __builtin_amdgcn_mfma_f32_16x16x32_f16(Ah[p][1], bl1, c2, 0, 0, 0);
      #pragma unroll
      for (int r = 0; r < 4; ++r) {
        const int s = p * 4 + r;
        float dot = fmaf(c2[r], (1.0f / 2048.0f), c1[r]);
        float sq  = fmaxf(fmaf(-2.0f, dot, xne[s] + ync), 0.0f);
        float d   = 2.0f - __builtin_amdgcn_sqrtf(sq);   // raw v_sqrt_f32
        float e   = __expf(d);
        rsum[s] += e;
        if (d > rmax[s]) ridx[s] = col;        // cols ascend over jt -> first max
        rmax[s] = fmaxf(rmax[s], d);
        dv[s] = d; ev[s] = e;
      }
    }

    // ---- col partial: argmax tree over the lane's 8 rows (rows ascend with s,
    //      left-wins-tie at every pair -> first max), then LDS atomics ----
    float m01 = fmaxf(dv[0], dv[1]); int i01 = dv[1] > dv[0] ? 1 : 0;
    float m23 = fmaxf(dv[2], dv[3]); int i23 = dv[3] > dv[2] ? 3 : 2;
    float m45 = fmaxf(dv[4], dv[5]); int i45 = dv[5] > dv[4] ? 5 : 4;
    float m67 = fmaxf(dv[6], dv[7]); int i67 = dv[7] > dv[6] ? 7 : 6;
    float mA  = fmaxf(m01, m23);     int iA  = m23 > m01 ? i23 : i01;
    float mB  = fmaxf(m45, m67);     int iB  = m67 > m45 ? i67 : i45;
    float mC  = fmaxf(mA, mB);       int iC  = mB  > mA  ? iB  : iA;
    int crow  = ro + ((iC >> 2) << 4) + (iC & 3);
    float csum = ((ev[0] + ev[1]) + (ev[2] + ev[3])) + ((ev[4] + ev[5]) + (ev[6] + ev[7]));
    unsigned long long ckey =
        ((unsigned long long)f2key(mC) << 32) | (unsigned long long)(unsigned)(~(unsigned)crow);
    atomicMax(&lkey[jt * 16 + l15], ckey);     // ds_max_u64 (DS pipe)
    atomicAdd(&lsum[jt * 16 + l15], csum);     // ds_add_f32 (DS pipe)
  }

  // ---- row reduce: one butterfly over the 16 lane-columns, once per kernel ----
  unsigned long long rkk[8];
  #pragma unroll
  for (int s = 0; s < 8; ++s)
    rkk[s] = ((unsigned long long)f2key(rmax[s]) << 32) |
             (unsigned long long)(unsigned)(~(unsigned)ridx[s]);
  #pragma unroll
  for (int off = 1; off < 16; off <<= 1) {
    #pragma unroll
    for (int s = 0; s < 8; ++s) {
      rsum[s] += __shfl_xor(rsum[s], off);
      unsigned long long o = __shfl_xor(rkk[s], off);
      if (o > rkk[s]) rkk[s] = o;
    }
  }
  if (l15 == 0) {
    #pragma unroll
    for (int s = 0; s < 8; ++s) {
      int row = ro + ((s >> 2) << 4) + (s & 3);
      atomicMax(row_key + row, rkk[s]);
      atomicAdd(row_sum + row, rsum[s]);
    }
  }

  // ---- block-level col flush: 1 atomic pair per col ----
  __syncthreads();
  {
    int col = colbase + threadIdx.x;
    atomicMax(col_key + col, lkey[threadIdx.x]);
    atomicAdd(col_sum + col, lsum[threadIdx.x]);
  }
}

// ---------- finalize: unpack keys, mutual test, write outputs ----------
__global__ void finalize_kernel(const unsigned long long* __restrict__ row_key,
                                const float* __restrict__ row_sum,
                                const unsigned long long* __restrict__ col_key,
                                const float* __restrict__ col_sum,
                                float* __restrict__ out)
{
  int j = blockIdx.x * 256 + threadIdx.x;
  if (j >= MCOLS) return;
  unsigned long long ck = col_key[j];
  int   ci   = (int)(~(unsigned)ck);
  float cmax = key2f((unsigned)(ck >> 32));
  float lp_col = cmax - logf(col_sum[j]);

  unsigned long long rk = row_key[ci];
  int   rj   = (int)(~(unsigned)rk);
  float rmax = key2f((unsigned)(rk >> 32));
  float lp_row = rmax - logf(row_sum[ci]);

  int mut = (rj == j);
  out[j]                 = mut ? (lp_row + lp_col) : 0.0f;
  out[MCOLS + 2 * j + 0] = (float)ci;
  out[MCOLS + 2 * j + 1] = (float)j;
  out[3 * MCOLS + j]     = mut ? 1.0f : 0.0f;
}

extern "C" void kernel_launch(void* const* d_in, const int* in_sizes, int n_in,
                              void* d_out, int out_size, void* d_ws, size_t ws_size,
                              hipStream_t stream) {
  const float* x = (const float*)d_in[0];
  const float* y = (const float*)d_in[1];
  float* out = (float*)d_out;

  char* ws = (char*)d_ws;
  unsigned long long* row_key = (unsigned long long*)(ws);            // 64 KB
  unsigned long long* col_key = (unsigned long long*)(ws + 65536);    // 64 KB
  float* row_sum = (float*)(ws + 131072);                             // 32 KB
  float* col_sum = (float*)(ws + 163840);                             // 32 KB
  float* xn      = (float*)(ws + 196608);                             // 32 KB
  float* yn      = (float*)(ws + 229376);                             // 32 KB
  _Float16* xh = (_Float16*)(ws + 262144);                            // 1 MB each
  _Float16* xl = (_Float16*)(ws + 262144 + 1048576);
  _Float16* yh = (_Float16*)(ws + 262144 + 2097152);
  _Float16* yl = (_Float16*)(ws + 262144 + 3145728);

  convert_kernel<<<512, 256, 0, stream>>>(x, y, xh, xl, yh, yl, xn, yn,
                                          row_key, col_key, row_sum, col_sum);
  dim3 grid(MCOLS / 256, NROWS / 128);     // 32 x 64 blocks, 256 threads
  mfma_tile_kernel<<<grid, 256, 0, stream>>>(xh, xl, yh, yl, xn, yn,
                                             row_key, row_sum, col_key, col_sum);
  finalize_kernel<<<32, 256, 0, stream>>>(row_key, row_sum, col_key, col_sum, out);
}